// Round 4
// baseline (419.253 us; speedup 1.0000x reference)
//
#include <hip/hip_runtime.h>

typedef __bf16 bf16;
typedef __attribute__((ext_vector_type(8))) __bf16 bf16x8;
typedef __attribute__((ext_vector_type(4))) __bf16 bf16x4;
typedef __attribute__((ext_vector_type(4))) float f32x4;

// ---------------------------------------------------------------------------
// Workspace layout (bytes):
//   xh  : NHWC padded input, bf16 [130][130][512]        = 17,305,600
//   w1t : conv1 weights,     bf16 [9][512 oc][512 c]     =  4,718,592
//   w2p : packed head wts,   bf16 [80 oc2][512 c]        =     81,920
//   mid : conv1 output NHWC, bf16 [16384 px][512 oc]     = 16,777,216
// ---------------------------------------------------------------------------
#define WS_XH   0
#define WS_W1T  17305600
#define WS_W2P  22024192
#define WS_MID  22106112

#define OUT_CLS 786432
#define OUT_ROI 1179648

// ---------------- fused prep: zero border | w1 repack | w2 pack ------------
// grid = 132 (border) + 1024 (w1) + 160 (w2) = 1316 blocks
__global__ void prep_misc(int4* __restrict__ xh4,
                          const float* __restrict__ w1, bf16* __restrict__ w1t,
                          const float* __restrict__ loc_w,
                          const float* __restrict__ score_w,
                          bf16* __restrict__ w2p) {
  __shared__ float lds[2304];
  const int t = threadIdx.x;
  const int b = blockIdx.x;
  if (b < 132) {
    const int4 z = make_int4(0, 0, 0, 0);
    if (b < 130) {
      if (t < 64)       xh4[(b * 130 + 0) * 64 + t] = z;
      else if (t < 128) xh4[(b * 130 + 129) * 64 + (t - 64)] = z;
    } else {
      const int r = (b == 130) ? 0 : 129;
      for (int i = t; i < 8320; i += 256) xh4[r * 8320 + i] = z;
    }
  } else if (b < 132 + 1024) {
    const int bb = b - 132;
    const long base = (long)bb * 2304;
#pragma unroll
    for (int i = 0; i < 9; ++i) lds[i * 256 + t] = w1[base + i * 256 + t];
    __syncthreads();
    const int pair0 = bb * 256;   // pair = oc*512 + c
#pragma unroll
    for (int j = 0; j < 9; ++j)
      w1t[(long)j * 262144 + pair0 + t] = (bf16)lds[t * 9 + j];
  } else {
    const int idx = (b - 1156) * 256 + t;   // 80*512 = 40960
    const int c  = idx & 511;
    const int oc = idx >> 9;
    float v = 0.f;
    if (oc < 48)      v = loc_w[oc * 512 + c];
    else if (oc < 72) v = score_w[(oc - 48) * 512 + c];
    w2p[idx] = (bf16)v;
  }
}

// ---------------- prep: NCHW fp32 -> NHWC bf16 interior transpose ----------
// Store phase now emits bf16x8 (16B) per lane instead of scalar 2B.
__global__ void transpose_x(const float* __restrict__ x, bf16* __restrict__ xh) {
  __shared__ float lds[64][65];
  const int tid  = threadIdx.x;
  const int ct   = blockIdx.x & 7;          // 64-channel tile
  const int colt = (blockIdx.x >> 3) & 1;   // 64-col tile
  const int r    = 1 + (blockIdx.x >> 4);   // padded row 1..128
  const int c0   = ct * 64;
  const int col0 = 1 + colt * 64;
  const int lcol = tid & 63;
  const int coff = tid >> 6;
#pragma unroll
  for (int i = 0; i < 16; ++i) {
    const int cl = coff + i * 4;
    lds[cl][lcol] = x[(long)(c0 + cl) * 16384 + (r - 1) * 128 + (col0 - 1) + lcol];
  }
  __syncthreads();
#pragma unroll
  for (int i = 0; i < 2; ++i) {
    const int idx = i * 256 + tid;      // 512 tasks: 64 px x 8 channel-octs
    const int pxl = idx >> 3;
    const int oct = idx & 7;
    bf16x8 v;
#pragma unroll
    for (int e = 0; e < 8; ++e) v[e] = (bf16)lds[oct * 8 + e][pxl];
    *(bf16x8*)(xh + (long)(r * 130 + col0 + pxl) * 512 + c0 + oct * 8) = v;
  }
}

// ---------------- conv1: flatmm-style implicit GEMM ------------------------
// C[oc,px] = sum_{j,c} w1t[j][oc][c] * xh[(h+ky)*130 + w+kx][c]
// No LDS, no barriers in the K-loop: fragments load straight from global into
// VGPRs (weights 4.7MB + per-XCD xh band are L2-resident; round-3 FETCH=28MB
// proves re-reads are cache-served). This sidesteps the ~22 B/cyc/CU
// global_load_lds DMA wall that pinned rounds 1-3 at 114us.
// grid 2048 = 8 oc-tiles(64) x 128 h x 2 wseg; block = 2 waves.
// Each wave: 64oc x 64px tile, K split even/odd BK=32 stages (72 each),
// 2-deep register prefetch; one-time LDS reduce combines the K-halves.
__global__ __launch_bounds__(128, 3) void conv1_flat(
    const bf16* __restrict__ w1t, const bf16* __restrict__ xh,
    const float* __restrict__ bias1, bf16* __restrict__ mid) {
  __shared__ f32x4 red[16][64];   // 16 KB one-time K-half exchange
  const int tid  = threadIdx.x;
  const int wave = tid >> 6;
  const int lane = tid & 63;
  const int quad = lane >> 4;
  const int l15  = lane & 15;
  const int b    = blockIdx.x;
  const int oc0  = (b >> 8) * 64;
  const int r    = b & 255;
  const int h    = ((r & 7) << 4) | (r >> 4);   // XCD-band swizzle on h
  const int w0   = ((r >> 3) & 1) * 64;

  const int laneOff = l15 * 1024 + quad * 16;   // frag: 16 rows x 64B, 16B/lane
  const char* Abase = (const char*)w1t + (long)oc0 * 1024 + laneOff;
  const char* Bbase = (const char*)xh + laneOff;

  f32x4 acc[4][4];
#pragma unroll
  for (int i = 0; i < 4; ++i)
#pragma unroll
    for (int k = 0; k < 4; ++k) acc[i][k] = (f32x4){0.f, 0.f, 0.f, 0.f};

  bf16x8 a0[4], bb0[4], a1[4], bb1[4];

  auto loadf = [&](bf16x8* A, bf16x8* B, int g) {
    const int j  = g >> 4, ck = g & 15;
    const int ky = j / 3, kx = j - ky * 3;
    const char* aB = Abase + (long)j * 524288 + ck * 64;
    const char* bB = Bbase + (long)((h + ky) * 130 + w0 + kx) * 1024 + ck * 64;
#pragma unroll
    for (int mi = 0; mi < 4; ++mi) A[mi] = *(const bf16x8*)(aB + mi * 16384);
#pragma unroll
    for (int ni = 0; ni < 4; ++ni) B[ni] = *(const bf16x8*)(bB + ni * 16384);
  };
  auto domfma = [&](bf16x8* A, bf16x8* B) {
#pragma unroll
    for (int mi = 0; mi < 4; ++mi)
#pragma unroll
      for (int ni = 0; ni < 4; ++ni)
        acc[mi][ni] = __builtin_amdgcn_mfma_f32_16x16x32_bf16(
            A[mi], B[ni], acc[mi][ni], 0, 0, 0);
  };

  // wave w owns global stages g = 2t + w, t = 0..71 (even/odd K-split)
  loadf(a0, bb0, wave);
  for (int t = 0; t < 72; t += 2) {
    loadf(a1, bb1, (t + 1) * 2 + wave);
    domfma(a0, bb0);
    if (t + 2 < 72) loadf(a0, bb0, (t + 2) * 2 + wave);
    domfma(a1, bb1);
  }

  // combine K-halves
  if (wave == 1) {
#pragma unroll
    for (int mi = 0; mi < 4; ++mi)
#pragma unroll
      for (int ni = 0; ni < 4; ++ni) red[mi * 4 + ni][lane] = acc[mi][ni];
  }
  __syncthreads();
  if (wave == 1) return;
#pragma unroll
  for (int mi = 0; mi < 4; ++mi)
#pragma unroll
    for (int ni = 0; ni < 4; ++ni) acc[mi][ni] += red[mi * 4 + ni][lane];

  // epilogue: bias + relu, bf16 NHWC store
  const int px0 = h * 128 + w0;
#pragma unroll
  for (int mi = 0; mi < 4; ++mi) {
    const int oc = oc0 + mi * 16 + quad * 4;
    const float bv0 = bias1[oc], bv1 = bias1[oc + 1];
    const float bv2 = bias1[oc + 2], bv3 = bias1[oc + 3];
#pragma unroll
    for (int ni = 0; ni < 4; ++ni) {
      const int px = px0 + ni * 16 + l15;
      f32x4 a = acc[mi][ni];
      float t0 = a[0] + bv0; t0 = t0 > 0.f ? t0 : 0.f;
      float t1 = a[1] + bv1; t1 = t1 > 0.f ? t1 : 0.f;
      float t2 = a[2] + bv2; t2 = t2 > 0.f ? t2 : 0.f;
      float t3 = a[3] + bv3; t3 = t3 > 0.f ? t3 : 0.f;
      bf16x4 v = {(bf16)t0, (bf16)t1, (bf16)t2, (bf16)t3};
      *(bf16x4*)(mid + (long)px * 512 + oc) = v;
    }
  }
}

// ---------------- head: barrier-free K-split GEMM + anchor decode ----------
__global__ __launch_bounds__(256) void head_gemm(
    const bf16* __restrict__ w2p, const bf16* __restrict__ mid,
    const float* __restrict__ loc_b, const float* __restrict__ score_b,
    float* __restrict__ out) {
  __shared__ f32x4 red[3][64][5];
  const int tid  = threadIdx.x;
  const int wave = tid >> 6;
  const int lane = tid & 63;
  const int quad = lane >> 4;
  const int l15  = lane & 15;
  const int px0  = blockIdx.x * 16;
  const bf16* mB = mid + (long)px0 * 512;

  f32x4 acc[5];
#pragma unroll
  for (int i = 0; i < 5; ++i) acc[i] = (f32x4){0.f, 0.f, 0.f, 0.f};

#pragma unroll
  for (int st = 0; st < 4; ++st) {
    const int k0 = wave * 128 + st * 32;
    bf16x8 bfr = *(const bf16x8*)(mB + (long)l15 * 512 + k0 + quad * 8);
#pragma unroll
    for (int mi = 0; mi < 5; ++mi) {
      bf16x8 af = *(const bf16x8*)(w2p + (long)(mi * 16 + l15) * 512 + k0 + quad * 8);
      acc[mi] = __builtin_amdgcn_mfma_f32_16x16x32_bf16(af, bfr, acc[mi], 0, 0, 0);
    }
  }

  if (wave > 0) {
#pragma unroll
    for (int mi = 0; mi < 5; ++mi) red[wave - 1][lane][mi] = acc[mi];
  }
  __syncthreads();
  if (wave != 0) return;
#pragma unroll
  for (int w = 0; w < 3; ++w)
#pragma unroll
    for (int mi = 0; mi < 5; ++mi) acc[mi] += red[w][lane][mi];

  const int p    = px0 + l15;
  const int hh   = p >> 7;
  const int wcol = p & 127;
  const float cx = 16.f * (float)hh;
  const float cy = 16.f * (float)wcol;
  const float s0 = quad == 0 ? 45.f : quad == 1 ? 91.f : quad == 2 ? 181.f : 362.f;
  const float s1 = quad == 0 ? 32.f : quad == 1 ? 64.f : quad == 2 ? 128.f : 256.f;
  const float s2 = quad == 0 ? 23.f : quad == 1 ? 45.f : quad == 2 ? 91.f : 181.f;
  const float aw[3] = {s0, s1, s2};
  const float ah[3] = {s2, s1, s0};
#pragma unroll
  for (int mi = 0; mi < 5; ++mi) {
#pragma unroll
    for (int r = 0; r < 4; ++r) {
      const int oc2 = mi * 16 + quad * 4 + r;
      float v = acc[mi][r];
      if (mi < 3) {
        v += loc_b[oc2];
        out[p * 48 + oc2] = v;
        float roi;
        if (r == 0)      roi = v * aw[mi] + cx;
        else if (r == 1) roi = v * ah[mi] + cy;
        else if (r == 2) roi = __expf(v) * aw[mi];
        else             roi = __expf(v) * ah[mi];
        out[OUT_ROI + p * 48 + oc2] = roi;
      } else {
        const int sc = oc2 - 48;
        if (sc < 24) {
          v += score_b[sc];
          out[OUT_CLS + p * 24 + sc] = v;
        }
      }
    }
  }
}

// ---------------------------------------------------------------------------
extern "C" void kernel_launch(void* const* d_in, const int* in_sizes, int n_in,
                              void* d_out, int out_size, void* d_ws, size_t ws_size,
                              hipStream_t stream) {
  (void)in_sizes; (void)n_in; (void)out_size; (void)ws_size;
  const float* x       = (const float*)d_in[0];
  const float* conv1_w = (const float*)d_in[1];
  const float* conv1_b = (const float*)d_in[2];
  const float* score_w = (const float*)d_in[3];
  const float* score_b = (const float*)d_in[4];
  const float* loc_w   = (const float*)d_in[5];
  const float* loc_b   = (const float*)d_in[6];
  char* ws = (char*)d_ws;
  bf16* xh  = (bf16*)(ws + WS_XH);
  bf16* w1t = (bf16*)(ws + WS_W1T);
  bf16* w2p = (bf16*)(ws + WS_W2P);
  bf16* mid = (bf16*)(ws + WS_MID);
  float* out = (float*)d_out;

  hipLaunchKernelGGL(prep_misc,   dim3(1316), dim3(256), 0, stream,
                     (int4*)xh, conv1_w, w1t, loc_w, score_w, w2p);
  hipLaunchKernelGGL(transpose_x, dim3(2048), dim3(256), 0, stream, x, xh);
  hipLaunchKernelGGL(conv1_flat,  dim3(2048), dim3(128), 0, stream, w1t, xh, conv1_b, mid);
  hipLaunchKernelGGL(head_gemm,   dim3(1024), dim3(256), 0, stream, w2p, mid, loc_b, score_b, out);
}

// Round 5
// 206.896 us; speedup vs baseline: 2.0264x; 2.0264x over previous
//
#include <hip/hip_runtime.h>

typedef __bf16 bf16;
typedef __attribute__((ext_vector_type(8))) __bf16 bf16x8;
typedef __attribute__((ext_vector_type(4))) __bf16 bf16x4;
typedef __attribute__((ext_vector_type(4))) float f32x4;

__device__ __forceinline__ void gload16(const void* g, void* l) {
  __builtin_amdgcn_global_load_lds(
      (__attribute__((address_space(1))) void*)(g),
      (__attribute__((address_space(3))) void*)(l), 16, 0, 0);
}

// ---------------------------------------------------------------------------
// Workspace layout (bytes):
//   xh  : NHWC padded input, bf16 [130][130][512]        = 17,305,600
//   w1t : conv1 weights,     bf16 [9][512 oc][512 c]     =  4,718,592
//   w2p : packed head wts,   bf16 [80 oc2][512 c]        =     81,920
//   mid : conv1 output NHWC, bf16 [16384 px][512 oc]     = 16,777,216
// ---------------------------------------------------------------------------
#define WS_XH   0
#define WS_W1T  17305600
#define WS_W2P  22024192
#define WS_MID  22106112

#define OUT_CLS 786432
#define OUT_ROI 1179648

// ---------------- fused prep: border | w1 repack | w2 pack | transpose -----
// grid = 132 + 1024 + 160 + 2048 = 3364 blocks, 256 thr
__global__ void prep_all(int4* __restrict__ xh4,
                         const float* __restrict__ w1, bf16* __restrict__ w1t,
                         const float* __restrict__ loc_w,
                         const float* __restrict__ score_w,
                         bf16* __restrict__ w2p,
                         const float* __restrict__ x, bf16* __restrict__ xh) {
  __shared__ float lds[64][65];   // transpose tile; w1 path reuses first 2304
  float* ldsf = &lds[0][0];
  const int t = threadIdx.x;
  const int b = blockIdx.x;
  if (b < 132) {                       // ---- xh halo border zeroing
    const int4 z = make_int4(0, 0, 0, 0);
    if (b < 130) {
      if (t < 64)       xh4[(b * 130 + 0) * 64 + t] = z;
      else if (t < 128) xh4[(b * 130 + 129) * 64 + (t - 64)] = z;
    } else {
      const int r = (b == 130) ? 0 : 129;
      for (int i = t; i < 8320; i += 256) xh4[r * 8320 + i] = z;
    }
  } else if (b < 1156) {               // ---- w1 [oc][c][3][3] -> w1t[j][oc][c]
    const int bb = b - 132;
    const long base = (long)bb * 2304;
#pragma unroll
    for (int i = 0; i < 9; ++i) ldsf[i * 256 + t] = w1[base + i * 256 + t];
    __syncthreads();
    const int pair0 = bb * 256;        // pair = oc*512 + c
#pragma unroll
    for (int j = 0; j < 9; ++j)
      w1t[(long)j * 262144 + pair0 + t] = (bf16)ldsf[t * 9 + j];
  } else if (b < 1316) {               // ---- pack loc_w+score_w -> w2p[80][512]
    const int idx = (b - 1156) * 256 + t;
    const int c  = idx & 511;
    const int oc = idx >> 9;
    float v = 0.f;
    if (oc < 48)      v = loc_w[oc * 512 + c];
    else if (oc < 72) v = score_w[(oc - 48) * 512 + c];
    w2p[idx] = (bf16)v;
  } else {                             // ---- NCHW fp32 -> NHWC bf16 transpose
    const int bb   = b - 1316;
    const int ct   = bb & 7;
    const int colt = (bb >> 3) & 1;
    const int r    = 1 + (bb >> 4);
    const int c0   = ct * 64;
    const int col0 = 1 + colt * 64;
    const int lcol = t & 63;
    const int coff = t >> 6;
#pragma unroll
    for (int i = 0; i < 16; ++i) {
      const int cl = coff + i * 4;
      lds[cl][lcol] = x[(long)(c0 + cl) * 16384 + (r - 1) * 128 + (col0 - 1) + lcol];
    }
    __syncthreads();
#pragma unroll
    for (int i = 0; i < 2; ++i) {
      const int idx = i * 256 + t;     // 512 tasks: 64 px x 8 channel-octs
      const int pxl = idx >> 3;
      const int oct = idx & 7;
      bf16x8 v;
#pragma unroll
      for (int e = 0; e < 8; ++e) v[e] = (bf16)lds[oct * 8 + e][pxl];
      *(bf16x8*)(xh + (long)(r * 130 + col0 + pxl) * 512 + c0 + oct * 8) = v;
    }
  }
}

// ---------------- conv1: B-reuse implicit GEMM ------------------------------
// mid[px][oc] = relu(b1 + sum_{ky,kx,c} w1t[ky*3+kx][oc][c] * xh[h+ky][w+kx][c])
// 256 blocks (1/CU) = 2 oc-halves(256) x 128 h-rows. 512 thr = 8 waves,
// wave grid 4(oc) x 2(px): each wave 64oc x 64px, acc 4x4 f32x4.
// K-loop restructured for conv's B-reuse: per 32-ch chunk ck, stage the 3 xh
// rows (130 px) ONCE (25 KB), then 9 j-slots reuse them at kx-shifted LDS
// offsets; only A (256oc x 32c = 16 KB, double-buffered) is staged per slot.
// Slots per CU: 144 + 16 B-slots (vs 288 x 16KB in the round-1 structure).
__global__ __launch_bounds__(512, 1) void conv1_big(
    const bf16* __restrict__ w1t, const bf16* __restrict__ xh,
    const float* __restrict__ bias1, bf16* __restrict__ mid) {
  __shared__ bf16 Abuf[2][256 * 32];     // 16 KB x2
  __shared__ bf16 Bbuf[3 * 132 * 32];    // 25.3 KB (3 rows x 132 cols x 32ch)
  const int tid  = threadIdx.x;
  const int wave = tid >> 6;
  const int lane = tid & 63;
  const int quad = lane >> 4;
  const int l15  = lane & 15;
  const int wr = wave >> 1, wc = wave & 1;
  const int blk  = blockIdx.x;
  const int oc_t = (blk >> 3) & 1;
  const int h    = ((blk & 7) << 4) + (blk >> 4);   // XCD h-band swizzle
  const int oc0  = oc_t * 256;

  const char* Ag = (const char*)w1t + (long)oc0 * 1024;  // +j*524288+oc*1024+c*2
  const char* Bg = (const char*)xh;

  auto stageA = [&](int j, int ck, int buf) {
    const char* src = Ag + (long)j * 524288 + ck * 64;
    char* dst = (char*)&Abuf[buf][0];
#pragma unroll
    for (int c2 = 0; c2 < 2; ++c2) {
      const int r0 = wave * 32 + c2 * 16;   // 16 oc-rows x 64B per call
      gload16(src + (long)(r0 + (lane >> 2)) * 1024 + (lane & 3) * 16,
              dst + r0 * 64);
    }
  };
  auto stageB = [&](int ck) {
#pragma unroll
    for (int ky = 0; ky < 3; ++ky) {
      const char* src = Bg + (long)((h + ky) * 130) * 1024 + ck * 64;
      char* dst = (char*)Bbuf + ky * 8448;          // row stride 132*64
      // cols [16w,16w+16): 8 full calls (one per wave)
      gload16(src + (long)(wave * 16 + (lane >> 2)) * 1024 + (lane & 3) * 16,
              dst + wave * 1024);
    }
    if (wave == 0 && lane < 8) {                    // cols 128,129 partial
#pragma unroll
      for (int ky = 0; ky < 3; ++ky) {
        const char* src = Bg + (long)((h + ky) * 130) * 1024 + ck * 64;
        char* dst = (char*)Bbuf + ky * 8448;
        gload16(src + (long)(128 + (lane >> 2)) * 1024 + (lane & 3) * 16,
                dst + 8192);
      }
    }
  };

  f32x4 acc[4][4];
#pragma unroll
  for (int i = 0; i < 4; ++i)
#pragma unroll
    for (int k = 0; k < 4; ++k) acc[i][k] = (f32x4){0.f, 0.f, 0.f, 0.f};

  auto compute = [&](int ky, int kx, int ab) {
    bf16x8 af[4], bfr[4];
#pragma unroll
    for (int mi = 0; mi < 4; ++mi)
      af[mi] = *(const bf16x8*)((const char*)&Abuf[ab][0] +
                                (wr * 64 + mi * 16 + l15) * 64 + quad * 16);
#pragma unroll
    for (int ni = 0; ni < 4; ++ni) {
      const int col = wc * 64 + ni * 16 + l15 + kx;
      bfr[ni] = *(const bf16x8*)((const char*)Bbuf + ky * 8448 + col * 64 + quad * 16);
    }
#pragma unroll
    for (int mi = 0; mi < 4; ++mi)
#pragma unroll
      for (int ni = 0; ni < 4; ++ni)
        acc[mi][ni] = __builtin_amdgcn_mfma_f32_16x16x32_bf16(
            af[mi], bfr[ni], acc[mi][ni], 0, 0, 0);
  };

  stageB(0);
  stageA(0, 0, 0);
  asm volatile("s_waitcnt vmcnt(0)" ::: "memory");
  __builtin_amdgcn_s_barrier();

  int ab = 0;
  for (int ck = 0; ck < 16; ++ck) {
    for (int j = 0; j < 9; ++j) {
      if (j < 8)          stageA(j + 1, ck, ab ^ 1);
      else if (ck < 15)   stageA(0, ck + 1, ab ^ 1);
      compute(j / 3, j - (j / 3) * 3, ab);
      asm volatile("s_waitcnt vmcnt(0)" ::: "memory");
      __builtin_amdgcn_s_barrier();
      ab ^= 1;
    }
    if (ck < 15) {        // B restage: reads of Bbuf all done (post-barrier)
      stageB(ck + 1);
      asm volatile("s_waitcnt vmcnt(0)" ::: "memory");
      __builtin_amdgcn_s_barrier();
    }
  }

  // epilogue: bias + relu, bf16 NHWC store
#pragma unroll
  for (int mi = 0; mi < 4; ++mi) {
    const int oc = oc0 + wr * 64 + mi * 16 + quad * 4;
    const float bv0 = bias1[oc], bv1 = bias1[oc + 1];
    const float bv2 = bias1[oc + 2], bv3 = bias1[oc + 3];
#pragma unroll
    for (int ni = 0; ni < 4; ++ni) {
      const int px = wc * 64 + ni * 16 + l15;
      f32x4 a = acc[mi][ni];
      float t0 = a[0] + bv0; t0 = t0 > 0.f ? t0 : 0.f;
      float t1 = a[1] + bv1; t1 = t1 > 0.f ? t1 : 0.f;
      float t2 = a[2] + bv2; t2 = t2 > 0.f ? t2 : 0.f;
      float t3 = a[3] + bv3; t3 = t3 > 0.f ? t3 : 0.f;
      bf16x4 v = {(bf16)t0, (bf16)t1, (bf16)t2, (bf16)t3};
      *(bf16x4*)(mid + (long)(h * 128 + px) * 512 + oc) = v;
    }
  }
}

// ---------------- head: barrier-free K-split GEMM + anchor decode ----------
__global__ __launch_bounds__(256) void head_gemm(
    const bf16* __restrict__ w2p, const bf16* __restrict__ mid,
    const float* __restrict__ loc_b, const float* __restrict__ score_b,
    float* __restrict__ out) {
  __shared__ f32x4 red[3][64][5];
  const int tid  = threadIdx.x;
  const int wave = tid >> 6;
  const int lane = tid & 63;
  const int quad = lane >> 4;
  const int l15  = lane & 15;
  const int px0  = blockIdx.x * 16;
  const bf16* mB = mid + (long)px0 * 512;

  f32x4 acc[5];
#pragma unroll
  for (int i = 0; i < 5; ++i) acc[i] = (f32x4){0.f, 0.f, 0.f, 0.f};

#pragma unroll
  for (int st = 0; st < 4; ++st) {
    const int k0 = wave * 128 + st * 32;
    bf16x8 bfr = *(const bf16x8*)(mB + (long)l15 * 512 + k0 + quad * 8);
#pragma unroll
    for (int mi = 0; mi < 5; ++mi) {
      bf16x8 af = *(const bf16x8*)(w2p + (long)(mi * 16 + l15) * 512 + k0 + quad * 8);
      acc[mi] = __builtin_amdgcn_mfma_f32_16x16x32_bf16(af, bfr, acc[mi], 0, 0, 0);
    }
  }

  if (wave > 0) {
#pragma unroll
    for (int mi = 0; mi < 5; ++mi) red[wave - 1][lane][mi] = acc[mi];
  }
  __syncthreads();
  if (wave != 0) return;
#pragma unroll
  for (int w = 0; w < 3; ++w)
#pragma unroll
    for (int mi = 0; mi < 5; ++mi) acc[mi] += red[w][lane][mi];

  const int p    = px0 + l15;
  const int hh   = p >> 7;
  const int wcol = p & 127;
  const float cx = 16.f * (float)hh;
  const float cy = 16.f * (float)wcol;
  const float s0 = quad == 0 ? 45.f : quad == 1 ? 91.f : quad == 2 ? 181.f : 362.f;
  const float s1 = quad == 0 ? 32.f : quad == 1 ? 64.f : quad == 2 ? 128.f : 256.f;
  const float s2 = quad == 0 ? 23.f : quad == 1 ? 45.f : quad == 2 ? 91.f : 181.f;
  const float aw[3] = {s0, s1, s2};
  const float ah[3] = {s2, s1, s0};
#pragma unroll
  for (int mi = 0; mi < 5; ++mi) {
#pragma unroll
    for (int r = 0; r < 4; ++r) {
      const int oc2 = mi * 16 + quad * 4 + r;
      float v = acc[mi][r];
      if (mi < 3) {
        v += loc_b[oc2];
        out[p * 48 + oc2] = v;
        float roi;
        if (r == 0)      roi = v * aw[mi] + cx;
        else if (r == 1) roi = v * ah[mi] + cy;
        else if (r == 2) roi = __expf(v) * aw[mi];
        else             roi = __expf(v) * ah[mi];
        out[OUT_ROI + p * 48 + oc2] = roi;
      } else {
        const int sc = oc2 - 48;
        if (sc < 24) {
          v += score_b[sc];
          out[OUT_CLS + p * 24 + sc] = v;
        }
      }
    }
  }
}

// ---------------------------------------------------------------------------
extern "C" void kernel_launch(void* const* d_in, const int* in_sizes, int n_in,
                              void* d_out, int out_size, void* d_ws, size_t ws_size,
                              hipStream_t stream) {
  (void)in_sizes; (void)n_in; (void)out_size; (void)ws_size;
  const float* x       = (const float*)d_in[0];
  const float* conv1_w = (const float*)d_in[1];
  const float* conv1_b = (const float*)d_in[2];
  const float* score_w = (const float*)d_in[3];
  const float* score_b = (const float*)d_in[4];
  const float* loc_w   = (const float*)d_in[5];
  const float* loc_b   = (const float*)d_in[6];
  char* ws = (char*)d_ws;
  bf16* xh  = (bf16*)(ws + WS_XH);
  bf16* w1t = (bf16*)(ws + WS_W1T);
  bf16* w2p = (bf16*)(ws + WS_W2P);
  bf16* mid = (bf16*)(ws + WS_MID);
  float* out = (float*)d_out;

  hipLaunchKernelGGL(prep_all,  dim3(3364), dim3(256), 0, stream,
                     (int4*)xh, conv1_w, w1t, loc_w, score_w, w2p, x, xh);
  hipLaunchKernelGGL(conv1_big, dim3(256),  dim3(512), 0, stream, w1t, xh, conv1_b, mid);
  hipLaunchKernelGGL(head_gemm, dim3(1024), dim3(256), 0, stream, w2p, mid, loc_b, score_b, out);
}

// Round 6
// 192.263 us; speedup vs baseline: 2.1806x; 1.0761x over previous
//
#include <hip/hip_runtime.h>

typedef __bf16 bf16;
typedef __attribute__((ext_vector_type(8))) __bf16 bf16x8;
typedef __attribute__((ext_vector_type(4))) __bf16 bf16x4;
typedef __attribute__((ext_vector_type(4))) float f32x4;

__device__ __forceinline__ void gload16(const void* g, void* l) {
  __builtin_amdgcn_global_load_lds(
      (__attribute__((address_space(1))) void*)(g),
      (__attribute__((address_space(3))) void*)(l), 16, 0, 0);
}

// ---------------------------------------------------------------------------
// Workspace layout (bytes):
//   xh  : NHWC padded input, bf16 [130][130][512]        = 17,305,600
//   w1t : conv1 weights,     bf16 [9][512 oc][512 c]     =  4,718,592
//   w2p : packed head wts,   bf16 [80 oc2][512 c]        =     81,920
//   mid : conv1 output NHWC, bf16 [16384 px][512 oc]     = 16,777,216
// ---------------------------------------------------------------------------
#define WS_XH   0
#define WS_W1T  17305600
#define WS_W2P  22024192
#define WS_MID  22106112

#define OUT_CLS 786432
#define OUT_ROI 1179648

// ---------------- fused prep: border | w1 repack | w2 pack | transpose -----
// grid = 132 + 1024 + 160 + 2048 = 3364 blocks, 256 thr
__global__ void prep_all(int4* __restrict__ xh4,
                         const float* __restrict__ w1, bf16* __restrict__ w1t,
                         const float* __restrict__ loc_w,
                         const float* __restrict__ score_w,
                         bf16* __restrict__ w2p,
                         const float* __restrict__ x, bf16* __restrict__ xh) {
  __shared__ float lds[64][65];
  float* ldsf = &lds[0][0];
  const int t = threadIdx.x;
  const int b = blockIdx.x;
  if (b < 132) {                       // ---- xh halo border zeroing
    const int4 z = make_int4(0, 0, 0, 0);
    if (b < 130) {
      if (t < 64)       xh4[(b * 130 + 0) * 64 + t] = z;
      else if (t < 128) xh4[(b * 130 + 129) * 64 + (t - 64)] = z;
    } else {
      const int r = (b == 130) ? 0 : 129;
      for (int i = t; i < 8320; i += 256) xh4[r * 8320 + i] = z;
    }
  } else if (b < 1156) {               // ---- w1 [oc][c][3][3] -> w1t[j][oc][c]
    const int bb = b - 132;
    const long base = (long)bb * 2304;
#pragma unroll
    for (int i = 0; i < 9; ++i) ldsf[i * 256 + t] = w1[base + i * 256 + t];
    __syncthreads();
    const int pair0 = bb * 256;        // pair = oc*512 + c
#pragma unroll
    for (int j = 0; j < 9; ++j)
      w1t[(long)j * 262144 + pair0 + t] = (bf16)ldsf[t * 9 + j];
  } else if (b < 1316) {               // ---- pack loc_w+score_w -> w2p[80][512]
    const int idx = (b - 1156) * 256 + t;
    const int c  = idx & 511;
    const int oc = idx >> 9;
    float v = 0.f;
    if (oc < 48)      v = loc_w[oc * 512 + c];
    else if (oc < 72) v = score_w[(oc - 48) * 512 + c];
    w2p[idx] = (bf16)v;
  } else {                             // ---- NCHW fp32 -> NHWC bf16 transpose
    const int bb   = b - 1316;
    const int ct   = bb & 7;
    const int colt = (bb >> 3) & 1;
    const int r    = 1 + (bb >> 4);
    const int c0   = ct * 64;
    const int col0 = 1 + colt * 64;
    const int lcol = t & 63;
    const int coff = t >> 6;
#pragma unroll
    for (int i = 0; i < 16; ++i) {
      const int cl = coff + i * 4;
      lds[cl][lcol] = x[(long)(c0 + cl) * 16384 + (r - 1) * 128 + (col0 - 1) + lcol];
    }
    __syncthreads();
#pragma unroll
    for (int i = 0; i < 2; ++i) {
      const int idx = i * 256 + t;
      const int pxl = idx >> 3;
      const int oct = idx & 7;
      bf16x8 v;
#pragma unroll
      for (int e = 0; e < 8; ++e) v[e] = (bf16)lds[oct * 8 + e][pxl];
      *(bf16x8*)(xh + (long)(r * 130 + col0 + pxl) * 512 + c0 + oct * 8) = v;
    }
  }
}

// ---------------- conv1 implicit GEMM: 3-deep rotating pipeline -------------
// C[oc,px] = sum_{j,c} w1t[j][oc][c] * xh[(h+ky)*130+(w+kx)][c]
// 512 blocks = 4 oc-tiles x 128 h-rows; 128x128 tile; 144 stages of BK=32.
// Rounds 1/3/5 all pinned at ~112us: the invariant is ~900cy L3-class load
// latency exposed once per barrier-slot (w1t 4.7MB + xh band exceed per-XCD
// L2 -> L2 misses). Fix: keep TWO stages in flight. Per slot:
//   s_waitcnt vmcnt(4)   // oldest stage landed (4 gloads/wave/stage);
//                        // newest stays in flight
//   s_barrier            // all waves' oldest stage visible in LDS
//   stage(s+2)           // refill the buffer freed 2 slots ago
//   compute(s)           // ds_read + 16 MFMA (~350cy) while s+1,s+2 fly
// Each stage gets ~2 slots (~1000cy) to land -> latency hidden, slot floor
// becomes compute. LDS swizzle keeps fragment reads 2-lanes/bank (free).
__global__ __launch_bounds__(256, 2) void conv1_gemm(
    const bf16* __restrict__ w1t, const bf16* __restrict__ xh,
    const float* __restrict__ b1, bf16* __restrict__ mid) {
  __shared__ bf16 A0[4096], B0[4096], A1[4096], B1[4096], A2[4096], B2[4096];
  const int tid  = threadIdx.x;
  const int wave = tid >> 6;
  const int lane = tid & 63;
  const int quad = lane >> 4;
  const int l15  = lane & 15;
  const int wr = wave >> 1, wc = wave & 1;
  const int blk     = blockIdx.x;
  const int oc_tile = blk >> 7;
  const int hraw    = blk & 127;
  const int h       = ((hraw & 7) << 4) + (hraw >> 3);   // XCD h-band swizzle
  const char* w1tB = (const char*)w1t + (long)oc_tile * 131072;
  const char* xhB  = (const char*)xh;
  const int srow = lane >> 2;                               // 16 rows/call
  const int ssw  = (((lane & 3) ^ ((lane >> 3) & 3)) << 4); // swizzled chunk
  const int swq  = (quad ^ ((l15 >> 1) & 3)) << 3;          // swizzled frag

  auto stage = [&](int s, bf16* At, bf16* Bt) {   // 4 gloads per wave
    const int j  = s >> 4, ck = s & 15;
    const int ky = j / 3, kx = j - ky * 3;
    const char* aB = w1tB + (long)j * 524288 + ck * 64;
    const char* bB = xhB + (long)((h + ky) * 130 + kx) * 1024 + ck * 64;
#pragma unroll
    for (int c = 0; c < 2; ++c) {
      const int r0 = wave * 32 + c * 16;
      gload16(aB + (long)(r0 + srow) * 1024 + ssw, (char*)At + r0 * 64);
      gload16(bB + (long)(r0 + srow) * 1024 + ssw, (char*)Bt + r0 * 64);
    }
  };

  f32x4 acc[4][4];
#pragma unroll
  for (int i = 0; i < 4; ++i)
#pragma unroll
    for (int k = 0; k < 4; ++k) acc[i][k] = (f32x4){0.f, 0.f, 0.f, 0.f};

  auto compute = [&](const bf16* A, const bf16* B) {
    bf16x8 af[4], bfr[4];
#pragma unroll
    for (int mi = 0; mi < 4; ++mi)
      af[mi] = *(const bf16x8*)&A[(wr * 64 + mi * 16 + l15) * 32 + swq];
#pragma unroll
    for (int ni = 0; ni < 4; ++ni)
      bfr[ni] = *(const bf16x8*)&B[(wc * 64 + ni * 16 + l15) * 32 + swq];
#pragma unroll
    for (int mi = 0; mi < 4; ++mi)
#pragma unroll
      for (int ni = 0; ni < 4; ++ni)
        acc[mi][ni] = __builtin_amdgcn_mfma_f32_16x16x32_bf16(
            af[mi], bfr[ni], acc[mi][ni], 0, 0, 0);
  };

#define WAIT4 asm volatile("s_waitcnt vmcnt(4)" ::: "memory")
#define WAIT0 asm volatile("s_waitcnt vmcnt(0)" ::: "memory")
#define BARR  __builtin_amdgcn_s_barrier()

  stage(0, A0, B0);
  stage(1, A1, B1);

  for (int g = 0; g < 47; ++g) {        // slots 0..140 (141 = 47*3)
    const int s = g * 3;
    WAIT4; BARR; stage(s + 2, A2, B2); compute(A0, B0);   // slot s
    WAIT4; BARR; stage(s + 3, A0, B0); compute(A1, B1);   // slot s+1
    WAIT4; BARR; stage(s + 4, A1, B1); compute(A2, B2);   // slot s+2
  }
  WAIT4; BARR; stage(143, A2, B2); compute(A0, B0);       // slot 141
  WAIT4; BARR; compute(A1, B1);                           // slot 142
  WAIT0; BARR; compute(A2, B2);                           // slot 143

#undef WAIT4
#undef WAIT0
#undef BARR

  // epilogue: bias + relu, store bf16 NHWC mid[px][oc]
#pragma unroll
  for (int mi = 0; mi < 4; ++mi) {
    const int oc = oc_tile * 128 + wr * 64 + mi * 16 + quad * 4;
    const float bv0 = b1[oc], bv1 = b1[oc + 1], bv2 = b1[oc + 2], bv3 = b1[oc + 3];
#pragma unroll
    for (int ni = 0; ni < 4; ++ni) {
      const int px = wc * 64 + ni * 16 + l15;
      f32x4 a = acc[mi][ni];
      float t0 = a[0] + bv0; t0 = t0 > 0.f ? t0 : 0.f;
      float t1 = a[1] + bv1; t1 = t1 > 0.f ? t1 : 0.f;
      float t2 = a[2] + bv2; t2 = t2 > 0.f ? t2 : 0.f;
      float t3 = a[3] + bv3; t3 = t3 > 0.f ? t3 : 0.f;
      bf16x4 v = {(bf16)t0, (bf16)t1, (bf16)t2, (bf16)t3};
      *(bf16x4*)(mid + (long)(h * 128 + px) * 512 + oc) = v;
    }
  }
}

// ---------------- head: barrier-free K-split GEMM + anchor decode ----------
__global__ __launch_bounds__(256) void head_gemm(
    const bf16* __restrict__ w2p, const bf16* __restrict__ mid,
    const float* __restrict__ loc_b, const float* __restrict__ score_b,
    float* __restrict__ out) {
  __shared__ f32x4 red[3][64][5];
  const int tid  = threadIdx.x;
  const int wave = tid >> 6;
  const int lane = tid & 63;
  const int quad = lane >> 4;
  const int l15  = lane & 15;
  const int px0  = blockIdx.x * 16;
  const bf16* mB = mid + (long)px0 * 512;

  f32x4 acc[5];
#pragma unroll
  for (int i = 0; i < 5; ++i) acc[i] = (f32x4){0.f, 0.f, 0.f, 0.f};

#pragma unroll
  for (int st = 0; st < 4; ++st) {
    const int k0 = wave * 128 + st * 32;
    bf16x8 bfr = *(const bf16x8*)(mB + (long)l15 * 512 + k0 + quad * 8);
#pragma unroll
    for (int mi = 0; mi < 5; ++mi) {
      bf16x8 af = *(const bf16x8*)(w2p + (long)(mi * 16 + l15) * 512 + k0 + quad * 8);
      acc[mi] = __builtin_amdgcn_mfma_f32_16x16x32_bf16(af, bfr, acc[mi], 0, 0, 0);
    }
  }

  if (wave > 0) {
#pragma unroll
    for (int mi = 0; mi < 5; ++mi) red[wave - 1][lane][mi] = acc[mi];
  }
  __syncthreads();
  if (wave != 0) return;
#pragma unroll
  for (int w = 0; w < 3; ++w)
#pragma unroll
    for (int mi = 0; mi < 5; ++mi) acc[mi] += red[w][lane][mi];

  const int p    = px0 + l15;
  const int hh   = p >> 7;
  const int wcol = p & 127;
  const float cx = 16.f * (float)hh;
  const float cy = 16.f * (float)wcol;
  const float s0 = quad == 0 ? 45.f : quad == 1 ? 91.f : quad == 2 ? 181.f : 362.f;
  const float s1 = quad == 0 ? 32.f : quad == 1 ? 64.f : quad == 2 ? 128.f : 256.f;
  const float s2 = quad == 0 ? 23.f : quad == 1 ? 45.f : quad == 2 ? 91.f : 181.f;
  const float aw[3] = {s0, s1, s2};
  const float ah[3] = {s2, s1, s0};
#pragma unroll
  for (int mi = 0; mi < 5; ++mi) {
#pragma unroll
    for (int r = 0; r < 4; ++r) {
      const int oc2 = mi * 16 + quad * 4 + r;
      float v = acc[mi][r];
      if (mi < 3) {
        v += loc_b[oc2];
        out[p * 48 + oc2] = v;
        float roi;
        if (r == 0)      roi = v * aw[mi] + cx;
        else if (r == 1) roi = v * ah[mi] + cy;
        else if (r == 2) roi = __expf(v) * aw[mi];
        else             roi = __expf(v) * ah[mi];
        out[OUT_ROI + p * 48 + oc2] = roi;
      } else {
        const int sc = oc2 - 48;
        if (sc < 24) {
          v += score_b[sc];
          out[OUT_CLS + p * 24 + sc] = v;
        }
      }
    }
  }
}

// ---------------------------------------------------------------------------
extern "C" void kernel_launch(void* const* d_in, const int* in_sizes, int n_in,
                              void* d_out, int out_size, void* d_ws, size_t ws_size,
                              hipStream_t stream) {
  (void)in_sizes; (void)n_in; (void)out_size; (void)ws_size;
  const float* x       = (const float*)d_in[0];
  const float* conv1_w = (const float*)d_in[1];
  const float* conv1_b = (const float*)d_in[2];
  const float* score_w = (const float*)d_in[3];
  const float* score_b = (const float*)d_in[4];
  const float* loc_w   = (const float*)d_in[5];
  const float* loc_b   = (const float*)d_in[6];
  char* ws = (char*)d_ws;
  bf16* xh  = (bf16*)(ws + WS_XH);
  bf16* w1t = (bf16*)(ws + WS_W1T);
  bf16* w2p = (bf16*)(ws + WS_W2P);
  bf16* mid = (bf16*)(ws + WS_MID);
  float* out = (float*)d_out;

  hipLaunchKernelGGL(prep_all,   dim3(3364), dim3(256), 0, stream,
                     (int4*)xh, conv1_w, w1t, loc_w, score_w, w2p, x, xh);
  hipLaunchKernelGGL(conv1_gemm, dim3(512),  dim3(256), 0, stream, w1t, xh, conv1_b, mid);
  hipLaunchKernelGGL(head_gemm,  dim3(1024), dim3(256), 0, stream, w2p, mid, loc_b, score_b, out);
}